// Round 1
// baseline (707.091 us; speedup 1.0000x reference)
//
#include <hip/hip_runtime.h>

#define SVOL (64 * 64 * 64)  // 262144 spatial sites per (n, c)

typedef float vfloat4 __attribute__((ext_vector_type(4)));
typedef unsigned int vuint4 __attribute__((ext_vector_type(4)));

__device__ __forceinline__ unsigned short f32_to_bf16_rne(float f) {
    unsigned int u = __float_as_uint(f);
    unsigned int r = u + 0x7FFFu + ((u >> 16) & 1u);  // round to nearest even
    return (unsigned short)(r >> 16);
}

// ---------------------------------------------------------------------------
// Phase 1: transpose+compress vol [N=8][C=32][S] fp32 -> volT [N][S][C] bf16.
// LDS-free: one thread per site. 32 coalesced 4B channel loads per thread
// (all independent -> full MLP, no bank conflicts, no __syncthreads, tiny
// VGPR footprint -> max occupancy). Pack pairs into uints, store the site's
// 64 B record as 4x16B. vol reads are nontemporal (read-once, don't evict
// volT which the gather wants resident in L2/L3).
// ---------------------------------------------------------------------------
__global__ __launch_bounds__(256) void transpose_bf16_kernel(
    const float* __restrict__ vol, unsigned short* __restrict__ volT) {
    const int t = threadIdx.x;
    const int n = blockIdx.y;
    const long s = (long)blockIdx.x * 256 + t;

    const float* src = vol + (long)n * 32 * SVOL + s;

    // Load all 32 channels (independent, coalesced 256B/wave each).
    float v[32];
#pragma unroll
    for (int c = 0; c < 32; ++c) {
        v[c] = __builtin_nontemporal_load(src + (long)c * SVOL);
    }

    // Pack: uint h holds channels (2h, 2h+1) little-endian — matches the
    // gather's fma_bf16pair (lo ushort = even channel).
    unsigned int r[16];
#pragma unroll
    for (int h = 0; h < 16; ++h) {
        r[h] = (unsigned int)f32_to_bf16_rne(v[2 * h]) |
               ((unsigned int)f32_to_bf16_rne(v[2 * h + 1]) << 16);
    }

    vuint4* dst = (vuint4*)volT + ((long)n * SVOL + s) * 4;
#pragma unroll
    for (int q = 0; q < 4; ++q) {
        vuint4 w;
        w.x = r[4 * q + 0];
        w.y = r[4 * q + 1];
        w.z = r[4 * q + 2];
        w.w = r[4 * q + 3];
        dst[q] = w;  // cached: gather reuses volT
    }
}

// ---------------------------------------------------------------------------
// Phase 2: one thread per output point; all 32 channels. Each corner is one
// 64 B burst (4x uint4) of bf16. ALL 8 corners are prefetched before any FMA
// so ~32 independent 16B loads are in flight per wave (latency-bound random
// gather -> MLP is the lever). launch_bounds(256,3) keeps >=3 waves/SIMD
// (~= current measured occupancy) while permitting the ~160-VGPR live set.
// ---------------------------------------------------------------------------
__device__ __forceinline__ void fma_bf16pair(float& a0, float& a1,
                                             unsigned int u, float w) {
    const float lo = __uint_as_float(u << 16);
    const float hi = __uint_as_float(u & 0xFFFF0000u);
    a0 = fmaf(w, lo, a0);
    a1 = fmaf(w, hi, a1);
}

__global__ __launch_bounds__(256, 3) void gather_bf16_kernel(
    const float* __restrict__ grid, const unsigned short* __restrict__ volT,
    float* __restrict__ out) {
    const long gidx = (long)blockIdx.x * 256 + threadIdx.x;
    const int n = (int)(gidx >> 18);  // SVOL == 2^18
    const int s = (int)(gidx & (SVOL - 1));

    const float x = __builtin_nontemporal_load(grid + gidx * 3 + 0);
    const float y = __builtin_nontemporal_load(grid + gidx * 3 + 1);
    const float z = __builtin_nontemporal_load(grid + gidx * 3 + 2);

    // align_corners=True: [-1,1] -> [0, 63]
    const float ix = (x + 1.0f) * 0.5f * 63.0f;
    const float iy = (y + 1.0f) * 0.5f * 63.0f;
    const float iz = (z + 1.0f) * 0.5f * 63.0f;

    const float fx = floorf(ix), fy = floorf(iy), fz = floorf(iz);
    const int ix0 = (int)fx, iy0 = (int)fy, iz0 = (int)fz;
    const float tx = ix - fx, ty = iy - fy, tz = iz - fz;

    float wx[2], wy[2], wz[2];
    int xc[2], yc[2], zc[2];
    wx[0] = (ix0 >= 0 && ix0 < 64) ? (1.0f - tx) : 0.0f;
    wx[1] = (ix0 + 1 >= 0 && ix0 + 1 < 64) ? tx : 0.0f;
    wy[0] = (iy0 >= 0 && iy0 < 64) ? (1.0f - ty) : 0.0f;
    wy[1] = (iy0 + 1 >= 0 && iy0 + 1 < 64) ? ty : 0.0f;
    wz[0] = (iz0 >= 0 && iz0 < 64) ? (1.0f - tz) : 0.0f;
    wz[1] = (iz0 + 1 >= 0 && iz0 + 1 < 64) ? tz : 0.0f;
    xc[0] = min(max(ix0, 0), 63);
    xc[1] = min(max(ix0 + 1, 0), 63);
    yc[0] = min(max(iy0, 0), 63);
    yc[1] = min(max(iy0 + 1, 0), 63);
    zc[0] = min(max(iz0, 0), 63);
    zc[1] = min(max(iz0 + 1, 0), 63);

    const vuint4* base = (const vuint4*)(volT + (long)n * SVOL * 32);

    // Weights + corner addresses first (cheap VALU), then ALL loads, then FMAs.
    float wk[8];
    const vuint4* cp[8];
#pragma unroll
    for (int k = 0; k < 8; ++k) {
        const int kx = k & 1;
        const int ky = (k >> 1) & 1;
        const int kz = k >> 2;
        wk[k] = wz[kz] * wy[ky] * wx[kx];
        const int site = (zc[kz] * 64 + yc[ky]) * 64 + xc[kx];
        cp[k] = base + (long)site * 4;  // 64 B = 32 bf16 channels
    }

    vuint4 cv[8][4];
#pragma unroll
    for (int k = 0; k < 8; ++k) {
#pragma unroll
        for (int q = 0; q < 4; ++q) cv[k][q] = cp[k][q];
    }

    float acc[32];
#pragma unroll
    for (int c = 0; c < 32; ++c) acc[c] = 0.0f;

#pragma unroll
    for (int k = 0; k < 8; ++k) {
        const float w = wk[k];
#pragma unroll
        for (int q = 0; q < 4; ++q) {
            const vuint4 v = cv[k][q];
            fma_bf16pair(acc[q * 8 + 0], acc[q * 8 + 1], v.x, w);
            fma_bf16pair(acc[q * 8 + 2], acc[q * 8 + 3], v.y, w);
            fma_bf16pair(acc[q * 8 + 4], acc[q * 8 + 5], v.z, w);
            fma_bf16pair(acc[q * 8 + 6], acc[q * 8 + 7], v.w, w);
        }
    }

    // out [N][C][S]: lane-consecutive s -> each channel store is coalesced.
    float* op = out + (long)n * 32 * SVOL + s;
#pragma unroll
    for (int c = 0; c < 32; ++c) {
        __builtin_nontemporal_store(acc[c], op + (long)c * SVOL);
    }
}

// ---------------------------------------------------------------------------
// Fallback (workspace too small): direct fp32 gather from [N,C,D,H,W].
// ---------------------------------------------------------------------------
__global__ __launch_bounds__(256) void gather_direct_kernel(
    const float* __restrict__ grid, const float* __restrict__ vol,
    float* __restrict__ out) {
    const long gidx = (long)blockIdx.x * 256 + threadIdx.x;
    const int n = (int)(gidx >> 18);
    const int s = (int)(gidx & (SVOL - 1));

    const float* g = grid + gidx * 3;
    const float ix = (g[0] + 1.0f) * 0.5f * 63.0f;
    const float iy = (g[1] + 1.0f) * 0.5f * 63.0f;
    const float iz = (g[2] + 1.0f) * 0.5f * 63.0f;

    const float fx = floorf(ix), fy = floorf(iy), fz = floorf(iz);
    const int ix0 = (int)fx, iy0 = (int)fy, iz0 = (int)fz;
    const float tx = ix - fx, ty = iy - fy, tz = iz - fz;

    float wx[2], wy[2], wz[2];
    int xc[2], yc[2], zc[2];
    wx[0] = (ix0 >= 0 && ix0 < 64) ? (1.0f - tx) : 0.0f;
    wx[1] = (ix0 + 1 < 64) ? tx : 0.0f;
    wy[0] = (iy0 >= 0 && iy0 < 64) ? (1.0f - ty) : 0.0f;
    wy[1] = (iy0 + 1 < 64) ? ty : 0.0f;
    wz[0] = (iz0 >= 0 && iz0 < 64) ? (1.0f - tz) : 0.0f;
    wz[1] = (iz0 + 1 < 64) ? tz : 0.0f;
    xc[0] = min(max(ix0, 0), 63);
    xc[1] = min(max(ix0 + 1, 0), 63);
    yc[0] = min(max(iy0, 0), 63);
    yc[1] = min(max(iy0 + 1, 0), 63);
    zc[0] = min(max(iz0, 0), 63);
    zc[1] = min(max(iz0 + 1, 0), 63);

    long offk[8];
    float wk[8];
#pragma unroll
    for (int k = 0; k < 8; ++k) {
        const int kx = k & 1, ky = (k >> 1) & 1, kz = k >> 2;
        offk[k] = (long)(zc[kz] * 64 + yc[ky]) * 64 + xc[kx];
        wk[k] = wz[kz] * wy[ky] * wx[kx];
    }

    const float* base = vol + (long)n * 32 * SVOL;
    float* op = out + (long)n * 32 * SVOL + s;
    for (int c = 0; c < 32; ++c) {
        const float* bc = base + (long)c * SVOL;
        float a = 0.0f;
#pragma unroll
        for (int k = 0; k < 8; ++k) a = fmaf(wk[k], bc[offk[k]], a);
        op[(long)c * SVOL] = a;
    }
}

extern "C" void kernel_launch(void* const* d_in, const int* in_sizes, int n_in,
                              void* d_out, int out_size, void* d_ws, size_t ws_size,
                              hipStream_t stream) {
    const float* vol = (const float*)d_in[0];   // [8,32,64,64,64] fp32
    const float* grid = (const float*)d_in[1];  // [8,64,64,64,3] fp32
    float* out = (float*)d_out;                 // [8,32,64,64,64] fp32

    const size_t needed = (size_t)8 * SVOL * 32 * sizeof(unsigned short);  // 128 MiB
    const int npoints_blocks = (8 * SVOL) / 256;                           // 8192

    if (ws_size >= needed) {
        unsigned short* volT = (unsigned short*)d_ws;
        transpose_bf16_kernel<<<dim3(1024, 8), 256, 0, stream>>>(vol, volT);
        gather_bf16_kernel<<<npoints_blocks, 256, 0, stream>>>(grid, volT, out);
    } else {
        gather_direct_kernel<<<npoints_blocks, 256, 0, stream>>>(grid, vol, out);
    }
}

// Round 2
// 632.785 us; speedup vs baseline: 1.1174x; 1.1174x over previous
//
#include <hip/hip_runtime.h>

#define SVOL (64 * 64 * 64)  // 262144 spatial sites per (n, c)

typedef float vfloat4 __attribute__((ext_vector_type(4)));
typedef unsigned int vuint4 __attribute__((ext_vector_type(4)));

__device__ __forceinline__ unsigned short f32_to_bf16_rne(float f) {
    unsigned int u = __float_as_uint(f);
    unsigned int r = u + 0x7FFFu + ((u >> 16) & 1u);  // round to nearest even
    return (unsigned short)(r >> 16);
}

// ---------------------------------------------------------------------------
// Phase 1: transpose+compress vol [N=8][C=32][S] fp32 -> volT [N][S][C] bf16.
// LDS-free: one thread per site, 32 coalesced channel loads, pack in regs,
// write the site's 64 B record as 4x16B. (Unchanged from R1 — no counters on
// it yet; do not blind-optimize.)
// ---------------------------------------------------------------------------
__global__ __launch_bounds__(256) void transpose_bf16_kernel(
    const float* __restrict__ vol, unsigned short* __restrict__ volT) {
    const int t = threadIdx.x;
    const int n = blockIdx.y;
    const long s = (long)blockIdx.x * 256 + t;

    const float* src = vol + (long)n * 32 * SVOL + s;

    float v[32];
#pragma unroll
    for (int c = 0; c < 32; ++c) {
        v[c] = __builtin_nontemporal_load(src + (long)c * SVOL);
    }

    unsigned int r[16];
#pragma unroll
    for (int h = 0; h < 16; ++h) {
        r[h] = (unsigned int)f32_to_bf16_rne(v[2 * h]) |
               ((unsigned int)f32_to_bf16_rne(v[2 * h + 1]) << 16);
    }

    vuint4* dst = (vuint4*)volT + ((long)n * SVOL + s) * 4;
#pragma unroll
    for (int q = 0; q < 4; ++q) {
        vuint4 w;
        w.x = r[4 * q + 0];
        w.y = r[4 * q + 1];
        w.z = r[4 * q + 2];
        w.w = r[4 * q + 3];
        dst[q] = w;  // cached: gather reuses volT
    }
}

// ---------------------------------------------------------------------------
// Phase 2 (quad-cooperative): 4 lanes per output point, each lane owns 8
// channels = 16 B of every 64 B corner record. A corner-load instruction has
// lanes 4p..4p+3 reading consecutive 16 B of the SAME line -> the TA merges
// them into ONE line request. Each corner line is touched exactly once
// (8 line-requests/point) vs the old layout's 32 divergent lane-requests
// across 4 instructions. This attacks the measured ~2.9 cyc/divergent-request
// TA serialization that made occupancy increases useless in R1.
// ---------------------------------------------------------------------------
__device__ __forceinline__ void fma_bf16pair(float& a0, float& a1,
                                             unsigned int u, float w) {
    const float lo = __uint_as_float(u << 16);
    const float hi = __uint_as_float(u & 0xFFFF0000u);
    a0 = fmaf(w, lo, a0);
    a1 = fmaf(w, hi, a1);
}

__global__ __launch_bounds__(256) void gather_bf16_kernel(
    const float* __restrict__ grid, const unsigned short* __restrict__ volT,
    float* __restrict__ out) {
    const int t = threadIdx.x;
    const int q = t & 3;                             // channel quad: c in [q*8, q*8+8)
    const long p = (long)blockIdx.x * 64 + (t >> 2); // output point (64 per block)
    const int n = (int)(p >> 18);                    // SVOL == 2^18
    const int s = (int)(p & (SVOL - 1));

    // 4 lanes of a quad read the same grid entry (same-line -> one request);
    // consecutive points' entries are contiguous (16 pts x 12 B per wave).
    const float x = grid[p * 3 + 0];
    const float y = grid[p * 3 + 1];
    const float z = grid[p * 3 + 2];

    // align_corners=True: [-1,1] -> [0, 63]
    const float ix = (x + 1.0f) * 0.5f * 63.0f;
    const float iy = (y + 1.0f) * 0.5f * 63.0f;
    const float iz = (z + 1.0f) * 0.5f * 63.0f;

    const float fx = floorf(ix), fy = floorf(iy), fz = floorf(iz);
    const int ix0 = (int)fx, iy0 = (int)fy, iz0 = (int)fz;
    const float tx = ix - fx, ty = iy - fy, tz = iz - fz;

    float wx[2], wy[2], wz[2];
    int xc[2], yc[2], zc[2];
    wx[0] = (ix0 >= 0 && ix0 < 64) ? (1.0f - tx) : 0.0f;
    wx[1] = (ix0 + 1 >= 0 && ix0 + 1 < 64) ? tx : 0.0f;
    wy[0] = (iy0 >= 0 && iy0 < 64) ? (1.0f - ty) : 0.0f;
    wy[1] = (iy0 + 1 >= 0 && iy0 + 1 < 64) ? ty : 0.0f;
    wz[0] = (iz0 >= 0 && iz0 < 64) ? (1.0f - tz) : 0.0f;
    wz[1] = (iz0 + 1 >= 0 && iz0 + 1 < 64) ? tz : 0.0f;
    xc[0] = min(max(ix0, 0), 63);
    xc[1] = min(max(ix0 + 1, 0), 63);
    yc[0] = min(max(iy0, 0), 63);
    yc[1] = min(max(iy0 + 1, 0), 63);
    zc[0] = min(max(iz0, 0), 63);
    zc[1] = min(max(iz0 + 1, 0), 63);

    float wk[8];
    int site[8];
#pragma unroll
    for (int k = 0; k < 8; ++k) {
        const int kx = k & 1;
        const int ky = (k >> 1) & 1;
        const int kz = k >> 2;
        wk[k] = wz[kz] * wy[ky] * wx[kx];
        site[k] = (zc[kz] * 64 + yc[ky]) * 64 + xc[kx];
    }

    // One 16 B load per corner per lane; quad lanes cover the 64 B record.
    const unsigned short* vb = volT + (long)n * SVOL * 32 + q * 8;
    vuint4 cv[8];
#pragma unroll
    for (int k = 0; k < 8; ++k) {
        cv[k] = *(const vuint4*)(vb + (long)site[k] * 32);
    }

    float acc[8];
#pragma unroll
    for (int c = 0; c < 8; ++c) acc[c] = 0.0f;

#pragma unroll
    for (int k = 0; k < 8; ++k) {
        const float w = wk[k];
        fma_bf16pair(acc[0], acc[1], cv[k].x, w);
        fma_bf16pair(acc[2], acc[3], cv[k].y, w);
        fma_bf16pair(acc[4], acc[5], cv[k].z, w);
        fma_bf16pair(acc[6], acc[7], cv[k].w, w);
    }

    // out [N][C][S]: per store instruction the wave writes 4 channel-segments
    // of 16 consecutive s (64 B each) -> 4 lines/instr, 8 instrs (same line
    // count as before at 1/4 the instructions).
    float* op = out + ((long)n * 32 + q * 8) * SVOL + s;
#pragma unroll
    for (int c = 0; c < 8; ++c) {
        __builtin_nontemporal_store(acc[c], op + (long)c * SVOL);
    }
}

// ---------------------------------------------------------------------------
// Fallback (workspace too small): direct fp32 gather from [N,C,D,H,W].
// ---------------------------------------------------------------------------
__global__ __launch_bounds__(256) void gather_direct_kernel(
    const float* __restrict__ grid, const float* __restrict__ vol,
    float* __restrict__ out) {
    const long gidx = (long)blockIdx.x * 256 + threadIdx.x;
    const int n = (int)(gidx >> 18);
    const int s = (int)(gidx & (SVOL - 1));

    const float* g = grid + gidx * 3;
    const float ix = (g[0] + 1.0f) * 0.5f * 63.0f;
    const float iy = (g[1] + 1.0f) * 0.5f * 63.0f;
    const float iz = (g[2] + 1.0f) * 0.5f * 63.0f;

    const float fx = floorf(ix), fy = floorf(iy), fz = floorf(iz);
    const int ix0 = (int)fx, iy0 = (int)fy, iz0 = (int)fz;
    const float tx = ix - fx, ty = iy - fy, tz = iz - fz;

    float wx[2], wy[2], wz[2];
    int xc[2], yc[2], zc[2];
    wx[0] = (ix0 >= 0 && ix0 < 64) ? (1.0f - tx) : 0.0f;
    wx[1] = (ix0 + 1 < 64) ? tx : 0.0f;
    wy[0] = (iy0 >= 0 && iy0 < 64) ? (1.0f - ty) : 0.0f;
    wy[1] = (iy0 + 1 < 64) ? ty : 0.0f;
    wz[0] = (iz0 >= 0 && iz0 < 64) ? (1.0f - tz) : 0.0f;
    wz[1] = (iz0 + 1 < 64) ? tz : 0.0f;
    xc[0] = min(max(ix0, 0), 63);
    xc[1] = min(max(ix0 + 1, 0), 63);
    yc[0] = min(max(iy0, 0), 63);
    yc[1] = min(max(iy0 + 1, 0), 63);
    zc[0] = min(max(iz0, 0), 63);
    zc[1] = min(max(iz0 + 1, 0), 63);

    long offk[8];
    float wk[8];
#pragma unroll
    for (int k = 0; k < 8; ++k) {
        const int kx = k & 1, ky = (k >> 1) & 1, kz = k >> 2;
        offk[k] = (long)(zc[kz] * 64 + yc[ky]) * 64 + xc[kx];
        wk[k] = wz[kz] * wy[ky] * wx[kx];
    }

    const float* base = vol + (long)n * 32 * SVOL;
    float* op = out + (long)n * 32 * SVOL + s;
    for (int c = 0; c < 32; ++c) {
        const float* bc = base + (long)c * SVOL;
        float a = 0.0f;
#pragma unroll
        for (int k = 0; k < 8; ++k) a = fmaf(wk[k], bc[offk[k]], a);
        op[(long)c * SVOL] = a;
    }
}

extern "C" void kernel_launch(void* const* d_in, const int* in_sizes, int n_in,
                              void* d_out, int out_size, void* d_ws, size_t ws_size,
                              hipStream_t stream) {
    const float* vol = (const float*)d_in[0];   // [8,32,64,64,64] fp32
    const float* grid = (const float*)d_in[1];  // [8,64,64,64,3] fp32
    float* out = (float*)d_out;                 // [8,32,64,64,64] fp32

    const size_t needed = (size_t)8 * SVOL * 32 * sizeof(unsigned short);  // 128 MiB
    const int npoints = 8 * SVOL;  // 2.1M output points

    if (ws_size >= needed) {
        unsigned short* volT = (unsigned short*)d_ws;
        transpose_bf16_kernel<<<dim3(1024, 8), 256, 0, stream>>>(vol, volT);
        // 64 points per 256-thread block (4 lanes per point)
        gather_bf16_kernel<<<npoints / 64, 256, 0, stream>>>(grid, volT, out);
    } else {
        gather_direct_kernel<<<npoints / 256, 256, 0, stream>>>(grid, vol, out);
    }
}